// Round 1
// baseline (1423.392 us; speedup 1.0000x reference)
//
#include <hip/hip_runtime.h>
#include <math.h>

#define B_  4
#define C_  256
#define CI_ 128
#define N_  4096

// ---------------------------------------------------------------------------
// Embedding conv1x1: out[b][n][ci] = sum_c in[b][c][n] * w[ci][c] + bias[ci]
// grid (N/64, B, 3), block 256.  which: 0=theta(x), 1=phi(src), 2=g(src)
// Lanes = n (coalesced input reads); weights are wave-uniform -> s_loads.
// ---------------------------------------------------------------------------
__global__ __launch_bounds__(256) void embed_kernel(
    const float* __restrict__ x, const float* __restrict__ src,
    const float* __restrict__ th_w, const float* __restrict__ th_b,
    const float* __restrict__ ph_w, const float* __restrict__ ph_b,
    const float* __restrict__ g_w,  const float* __restrict__ g_b,
    float* __restrict__ theta, float* __restrict__ phi, float* __restrict__ g)
{
    const int n0    = blockIdx.x * 64;
    const int b     = blockIdx.y;
    const int which = blockIdx.z;
    const float* in; const float* wm; const float* bias; float* out;
    if (which == 0)      { in = x;   wm = th_w; bias = th_b; out = theta; }
    else if (which == 1) { in = src; wm = ph_w; bias = ph_b; out = phi; }
    else                 { in = src; wm = g_w;  bias = g_b;  out = g; }

    const int t    = threadIdx.x;
    const int lane = t & 63;
    const int wv   = __builtin_amdgcn_readfirstlane(t >> 6); // wave-uniform ci slot
    const int n    = n0 + lane;
    const float* col = in + (size_t)b * C_ * N_ + n;

    float acc[32];
#pragma unroll
    for (int k = 0; k < 32; ++k) acc[k] = bias[wv + 4 * k];

    for (int c = 0; c < C_; c += 4) {
        float v0 = col[(size_t)(c + 0) * N_];
        float v1 = col[(size_t)(c + 1) * N_];
        float v2 = col[(size_t)(c + 2) * N_];
        float v3 = col[(size_t)(c + 3) * N_];
#pragma unroll
        for (int k = 0; k < 32; ++k) {
            const float* wr = wm + (wv + 4 * k) * C_ + c;  // wave-uniform -> s_load_dwordx4
            acc[k] += v0 * wr[0] + v1 * wr[1] + v2 * wr[2] + v3 * wr[3];
        }
    }
    float* orow = out + ((size_t)b * N_ + n) * CI_;
#pragma unroll
    for (int k = 0; k < 32; ++k) orow[wv + 4 * k] = acc[k];
}

// ---------------------------------------------------------------------------
// Flash attention, f32. Q=theta rows, K=phi rows, V=g rows (all [B][N][Ci]).
// grid (N/64, B), block 256 (tx=0..15 cols/ci, ty=0..15 row groups of 4).
// Per m-tile (32 K rows): S[64][32] via 4x2 register tiles, online softmax
// with 16-lane shfl_xor reduction, then PV with 4x8 register tiles.
// ---------------------------------------------------------------------------
__global__ __launch_bounds__(256, 2) void attn_kernel(
    const float* __restrict__ theta, const float* __restrict__ phi,
    const float* __restrict__ g, float* __restrict__ y)
{
    __shared__ float Qs[64][132];
    __shared__ float Ks[32][132];
    __shared__ float Vs[32][132];
    __shared__ float Ps[64][36];

    const int b  = blockIdx.y;
    const int n0 = blockIdx.x * 64;
    const int t  = threadIdx.x;
    const int tx = t & 15;
    const int ty = t >> 4;
    const int r0 = ty * 4;

    const float* qb = theta + ((size_t)b * N_ + n0) * CI_;
    for (int k = t; k < 64 * 32; k += 256) {
        int r = k >> 5, c4 = (k & 31) * 4;
        *(float4*)&Qs[r][c4] = *(const float4*)(qb + r * CI_ + c4);
    }

    float m_run[4], l_run[4], acc[4][8];
#pragma unroll
    for (int i = 0; i < 4; ++i) {
        m_run[i] = -INFINITY; l_run[i] = 0.f;
#pragma unroll
        for (int j = 0; j < 8; ++j) acc[i][j] = 0.f;
    }

    const float* kb = phi + (size_t)b * N_ * CI_;
    const float* vb = g   + (size_t)b * N_ * CI_;

    for (int m0 = 0; m0 < N_; m0 += 32) {
        __syncthreads();                       // protects K/V (and Q at iter 0)
        for (int k = t; k < 32 * 32; k += 256) {
            int r = k >> 5, c4 = (k & 31) * 4;
            *(float4*)&Ks[r][c4] = *(const float4*)(kb + (size_t)(m0 + r) * CI_ + c4);
            *(float4*)&Vs[r][c4] = *(const float4*)(vb + (size_t)(m0 + r) * CI_ + c4);
        }
        __syncthreads();

        // ---- S = Q K^T : rows r0..r0+3, cols {tx, tx+16} ----
        float s0[4], s1[4];
#pragma unroll
        for (int i = 0; i < 4; ++i) { s0[i] = 0.f; s1[i] = 0.f; }
        for (int c = 0; c < CI_; c += 4) {
            float4 ka = *(const float4*)&Ks[tx][c];
            float4 kc = *(const float4*)&Ks[tx + 16][c];
#pragma unroll
            for (int i = 0; i < 4; ++i) {
                float4 q = *(const float4*)&Qs[r0 + i][c];
                s0[i] += q.x * ka.x + q.y * ka.y + q.z * ka.z + q.w * ka.w;
                s1[i] += q.x * kc.x + q.y * kc.y + q.z * kc.z + q.w * kc.w;
            }
        }

        // ---- online softmax (state replicated across the 16 tx lanes) ----
        float alpha[4];
#pragma unroll
        for (int i = 0; i < 4; ++i) {
            float tm = fmaxf(s0[i], s1[i]);
#pragma unroll
            for (int d = 1; d < 16; d <<= 1) tm = fmaxf(tm, __shfl_xor(tm, d));
            float mn = fmaxf(m_run[i], tm);
            alpha[i] = __expf(m_run[i] - mn);
            m_run[i] = mn;
            float p0 = __expf(s0[i] - mn);
            float p1 = __expf(s1[i] - mn);
            float ls = p0 + p1;
#pragma unroll
            for (int d = 1; d < 16; d <<= 1) ls += __shfl_xor(ls, d);
            l_run[i] = l_run[i] * alpha[i] + ls;
            Ps[r0 + i][tx]      = p0;
            Ps[r0 + i][tx + 16] = p1;
        }
#pragma unroll
        for (int i = 0; i < 4; ++i)
#pragma unroll
            for (int j = 0; j < 8; ++j) acc[i][j] *= alpha[i];

        __syncthreads();                       // P visibility safety

        // ---- PV: rows r0..r0+3, ci {4tx..4tx+3, 64+4tx..64+4tx+3} ----
        for (int m = 0; m < 32; m += 4) {
            float pr[4][4];
#pragma unroll
            for (int i = 0; i < 4; ++i) {
                float4 pv = *(const float4*)&Ps[r0 + i][m];
                pr[i][0] = pv.x; pr[i][1] = pv.y; pr[i][2] = pv.z; pr[i][3] = pv.w;
            }
#pragma unroll
            for (int j = 0; j < 4; ++j) {
                float4 va = *(const float4*)&Vs[m + j][tx * 4];
                float4 vc = *(const float4*)&Vs[m + j][64 + tx * 4];
#pragma unroll
                for (int i = 0; i < 4; ++i) {
                    float p = pr[i][j];
                    acc[i][0] += p * va.x; acc[i][1] += p * va.y;
                    acc[i][2] += p * va.z; acc[i][3] += p * va.w;
                    acc[i][4] += p * vc.x; acc[i][5] += p * vc.y;
                    acc[i][6] += p * vc.z; acc[i][7] += p * vc.w;
                }
            }
        }
    }

    float* yb = y + ((size_t)b * N_ + n0) * CI_;
#pragma unroll
    for (int i = 0; i < 4; ++i) {
        float inv = 1.f / l_run[i];
        float4 va, vc;
        va.x = acc[i][0] * inv; va.y = acc[i][1] * inv;
        va.z = acc[i][2] * inv; va.w = acc[i][3] * inv;
        vc.x = acc[i][4] * inv; vc.y = acc[i][5] * inv;
        vc.z = acc[i][6] * inv; vc.w = acc[i][7] * inv;
        *(float4*)(yb + (r0 + i) * CI_ + tx * 4)      = va;
        *(float4*)(yb + (r0 + i) * CI_ + 64 + tx * 4) = vc;
    }
}

// ---------------------------------------------------------------------------
// Wz conv1x1 + BN partial sums:
// w_y[b][c][n] = wz_b[c] + sum_ci y[b][n][ci] * wz_w[c][ci]
// grid (N/64, B, 2), block 256.  Stages y tile transposed in LDS.
// ---------------------------------------------------------------------------
__global__ __launch_bounds__(256) void wz_kernel(
    const float* __restrict__ y, const float* __restrict__ wz_w,
    const float* __restrict__ wz_b, float* __restrict__ w_y,
    float* __restrict__ sums)
{
    __shared__ float ylds[128][65];
    const int n0   = blockIdx.x * 64;
    const int b    = blockIdx.y;
    const int z    = blockIdx.z;
    const int t    = threadIdx.x;
    const int lane = t & 63;
    const int wv   = __builtin_amdgcn_readfirstlane(t >> 6);

    const float* yb = y + ((size_t)b * N_ + n0) * CI_;
    for (int k = t; k < 64 * 32; k += 256) {
        int n = k >> 5, c4 = (k & 31) * 4;
        float4 v = *(const float4*)(yb + n * CI_ + c4);
        ylds[c4 + 0][n] = v.x; ylds[c4 + 1][n] = v.y;
        ylds[c4 + 2][n] = v.z; ylds[c4 + 3][n] = v.w;
    }
    __syncthreads();

    const int cbase = z * 128 + wv;
    float acc[32];
#pragma unroll
    for (int k = 0; k < 32; ++k) acc[k] = wz_b[cbase + 4 * k];

    for (int ci = 0; ci < CI_; ci += 4) {
        float v0 = ylds[ci + 0][lane], v1 = ylds[ci + 1][lane];
        float v2 = ylds[ci + 2][lane], v3 = ylds[ci + 3][lane];
#pragma unroll
        for (int k = 0; k < 32; ++k) {
            const float* wr = wz_w + (cbase + 4 * k) * CI_ + ci;  // wave-uniform
            acc[k] += v0 * wr[0] + v1 * wr[1] + v2 * wr[2] + v3 * wr[3];
        }
    }

    const int n = n0 + lane;
#pragma unroll
    for (int k = 0; k < 32; ++k) {
        int c = cbase + 4 * k;
        w_y[((size_t)b * C_ + c) * N_ + n] = acc[k];
        float s = acc[k], q = acc[k] * acc[k];
#pragma unroll
        for (int d = 1; d < 64; d <<= 1) {
            s += __shfl_xor(s, d);
            q += __shfl_xor(q, d);
        }
        if (lane == 0) {
            atomicAdd(&sums[c], s);
            atomicAdd(&sums[C_ + c], q);
        }
    }
}

// ---------------------------------------------------------------------------
// BN finalize + residual: out = (w_y - mean)*rsqrt(var+eps)*gamma + beta + src
// ---------------------------------------------------------------------------
__global__ __launch_bounds__(256) void final_kernel(
    const float* __restrict__ w_y, const float* __restrict__ src,
    const float* __restrict__ gamma, const float* __restrict__ beta,
    const float* __restrict__ sums, float* __restrict__ out)
{
    const float invN = 1.0f / (float)(B_ * N_);
    const size_t tot4 = (size_t)B_ * C_ * N_ / 4;
    size_t stride = (size_t)gridDim.x * blockDim.x;
    for (size_t i4 = (size_t)blockIdx.x * blockDim.x + threadIdx.x; i4 < tot4; i4 += stride) {
        size_t i = i4 * 4;
        int c = (int)((i / N_) % C_);
        float mean  = sums[c] * invN;
        float var   = sums[C_ + c] * invN - mean * mean;
        float scale = rsqrtf(var + 1e-5f) * gamma[c];
        float bb    = beta[c];
        float4 w = *(const float4*)(w_y + i);
        float4 s = *(const float4*)(src + i);
        float4 o;
        o.x = (w.x - mean) * scale + bb + s.x;
        o.y = (w.y - mean) * scale + bb + s.y;
        o.z = (w.z - mean) * scale + bb + s.z;
        o.w = (w.w - mean) * scale + bb + s.w;
        *(float4*)((float*)out + i) = o;
    }
}

extern "C" void kernel_launch(void* const* d_in, const int* in_sizes, int n_in,
                              void* d_out, int out_size, void* d_ws, size_t ws_size,
                              hipStream_t stream)
{
    const float* x     = (const float*)d_in[0];
    const float* src   = (const float*)d_in[1];
    const float* g_w   = (const float*)d_in[2];
    const float* g_b   = (const float*)d_in[3];
    const float* th_w  = (const float*)d_in[4];
    const float* th_b  = (const float*)d_in[5];
    const float* ph_w  = (const float*)d_in[6];
    const float* ph_b  = (const float*)d_in[7];
    const float* wz_w  = (const float*)d_in[8];
    const float* wz_b  = (const float*)d_in[9];
    const float* gamma = (const float*)d_in[10];
    const float* beta  = (const float*)d_in[11];

    float* ws    = (float*)d_ws;
    float* theta = ws;                       // 2,097,152
    float* phi   = ws + 2097152;             // 2,097,152
    float* g     = ws + 2 * 2097152;         // 2,097,152
    float* y     = ws + 3 * 2097152;         // 2,097,152
    float* w_y   = ws + 4 * 2097152;         // 4,194,304
    float* sums  = ws + 4 * 2097152 + 4194304; // 512

    hipMemsetAsync(sums, 0, 512 * sizeof(float), stream);

    embed_kernel<<<dim3(64, 4, 3), 256, 0, stream>>>(
        x, src, th_w, th_b, ph_w, ph_b, g_w, g_b, theta, phi, g);
    attn_kernel<<<dim3(64, 4), 256, 0, stream>>>(theta, phi, g, y);
    wz_kernel<<<dim3(64, 4, 2), 256, 0, stream>>>(y, wz_w, wz_b, w_y, sums);
    final_kernel<<<2048, 256, 0, stream>>>(w_y, src, gamma, beta, sums, (float*)d_out);
}

// Round 3
// 752.715 us; speedup vs baseline: 1.8910x; 1.8910x over previous
//
#include <hip/hip_runtime.h>
#include <math.h>

#define B_  4
#define C_  256
#define CI_ 128
#define N_  4096
#define D_  128

typedef short bf16x8 __attribute__((ext_vector_type(8)));
typedef float f32x4 __attribute__((ext_vector_type(4)));
typedef unsigned short u16;

__device__ __forceinline__ u16 f2bf(float x) {
    union { float f; unsigned u; } v; v.f = x;
    unsigned r = v.u + 0x7FFFu + ((v.u >> 16) & 1u);
    return (u16)(r >> 16);
}
__device__ __forceinline__ float bf2f(u16 u) {
    union { unsigned u; float f; } v; v.u = ((unsigned)u) << 16; return v.f;
}
__device__ __forceinline__ float lo2f(unsigned w) {
    union { unsigned u; float f; } v; v.u = w << 16; return v.f;
}
__device__ __forceinline__ float hi2f(unsigned w) {
    union { unsigned u; float f; } v; v.u = w & 0xFFFF0000u; return v.f;
}

// ---------------------------------------------------------------------------
// Embedding conv1x1, f32 weights in LDS (two passes of 64 ci), bf16 hi/lo out.
// grid (N/64, B, 3), block 256, dyn LDS 64KB.
// which: 0=theta(x)->hi/lo [n][ci], 1=phi(src)->hi/lo [n][ci], 2=g(src)->gt[ci][n]
// ---------------------------------------------------------------------------
__global__ __launch_bounds__(256) void embed_kernel(
    const float* __restrict__ x, const float* __restrict__ src,
    const float* __restrict__ g_w, const float* __restrict__ g_b,
    const float* __restrict__ th_w, const float* __restrict__ th_b,
    const float* __restrict__ ph_w, const float* __restrict__ ph_b,
    u16* __restrict__ th_hi, u16* __restrict__ th_lo,
    u16* __restrict__ ph_hi, u16* __restrict__ ph_lo,
    u16* __restrict__ gt)
{
    extern __shared__ float wlds[];          // 64*256 f32 = 64KB
    u16* obh = (u16*)wlds;                   // reuse after compute: [64n][64ci]
    u16* obl = (u16*)wlds + 4096;
    const int n0 = blockIdx.x * 64, b = blockIdx.y, which = blockIdx.z;
    const float *in, *wm, *bias;
    u16 *oh = nullptr, *ol = nullptr;
    if (which == 0)      { in = x;   wm = th_w; bias = th_b; oh = th_hi; ol = th_lo; }
    else if (which == 1) { in = src; wm = ph_w; bias = ph_b; oh = ph_hi; ol = ph_lo; }
    else                 { in = src; wm = g_w;  bias = g_b; }

    const int t = threadIdx.x, lane = t & 63, wv = t >> 6;
    const float* col = in + (size_t)b * C_ * N_ + (n0 + lane);

    for (int p = 0; p < 2; ++p) {
        __syncthreads();                     // protect LDS reuse across passes
        for (int i = 0; i < 16; ++i) {
            int e = i * 1024 + t * 4;
            *(float4*)&wlds[e] = *(const float4*)(wm + p * 64 * C_ + e);
        }
        __syncthreads();

        float acc[16];
#pragma unroll
        for (int k = 0; k < 16; ++k) acc[k] = bias[p * 64 + wv + 4 * k];

        for (int c = 0; c < C_; c += 4) {
            float v0 = col[(size_t)(c + 0) * N_];
            float v1 = col[(size_t)(c + 1) * N_];
            float v2 = col[(size_t)(c + 2) * N_];
            float v3 = col[(size_t)(c + 3) * N_];
#pragma unroll
            for (int k = 0; k < 16; ++k) {
                float4 w = *(const float4*)&wlds[(wv + 4 * k) * 256 + c]; // broadcast
                acc[k] += v0 * w.x + v1 * w.y + v2 * w.z + v3 * w.w;
            }
        }
        __syncthreads();                     // weights dead -> obuf

#pragma unroll
        for (int k = 0; k < 16; ++k) {
            int cil = wv + 4 * k;
            int off = lane * 64 + (cil ^ ((lane & 7) << 3));
            u16 h = f2bf(acc[k]);
            obh[off] = h;
            if (which < 2) obl[off] = f2bf(acc[k] - bf2f(h));
        }
        __syncthreads();

        if (which < 2) {
            for (int i = 0; i < 2; ++i) {
                int flat = t + 256 * i;
                int nn = flat >> 3, c8 = (flat & 7) * 8;
                int off = nn * 64 + (c8 ^ ((nn & 7) << 3));
                size_t gofs = ((size_t)b * N_ + n0 + nn) * CI_ + p * 64 + c8;
                *(bf16x8*)(oh + gofs) = *(const bf16x8*)&obh[off];
                *(bf16x8*)(ol + gofs) = *(const bf16x8*)&obl[off];
            }
        } else {
            for (int i = 0; i < 2; ++i) {
                int flat = t + 256 * i;
                int cil = flat >> 3, n8 = (flat & 7) * 8;
                bf16x8 v;
#pragma unroll
                for (int j = 0; j < 8; ++j)
                    v[j] = (short)obh[(n8 + j) * 64 + (cil ^ (((n8 + j) & 7) << 3))];
                *(bf16x8*)(gt + ((size_t)b * CI_ + p * 64 + cil) * N_ + n0 + n8) = v;
            }
        }
    }
}

// ---------------------------------------------------------------------------
// Flash attention, bf16 MFMA 16x16x32 with hi/lo split QK^T (f32-accurate
// logits): S = qh*kh + ql*kh + qh*kl.  grid (N/64, B), block 256 (4 waves).
// A/B frag: row/col = lane&15, k = 8*(lane>>4)+[0..7]
// C/D frag: col = lane&15, row = 4*(lane>>4)+reg   [m89]
// LDS XOR swizzle: idx = row*stride + (off8 ^ ((row&7)<<3)) in bf16 units.
// Output: y_t[b][ci][n] bf16.
// ---------------------------------------------------------------------------
__global__ __launch_bounds__(256) void attn_kernel(
    const u16* __restrict__ th_hi, const u16* __restrict__ th_lo,
    const u16* __restrict__ ph_hi, const u16* __restrict__ ph_lo,
    const u16* __restrict__ gt, u16* __restrict__ y_t)
{
    __shared__ u16 Ksh[64 * 128];
    __shared__ u16 Ksl[64 * 128];
    __shared__ u16 Vt[128 * 64];
    __shared__ u16 Pl[4][16 * 64];

    const int b = blockIdx.y, n0 = blockIdx.x * 64;
    const int t = threadIdx.x, wv = t >> 6, lane = t & 63;
    const int lq = lane & 15, lh = lane >> 4;
    const int q0 = n0 + wv * 16;

    bf16x8 qfh[4], qfl[4];
    {
        const u16* qph = th_hi + ((size_t)b * N_ + q0 + lq) * D_ + 8 * lh;
        const u16* qpl = th_lo + ((size_t)b * N_ + q0 + lq) * D_ + 8 * lh;
#pragma unroll
        for (int c = 0; c < 4; ++c) {
            qfh[c] = *(const bf16x8*)(qph + 32 * c);
            qfl[c] = *(const bf16x8*)(qpl + 32 * c);
        }
    }

    f32x4 O[8];
    float m_run[4], l_run[4];
#pragma unroll
    for (int j = 0; j < 8; ++j) O[j] = (f32x4){0.f, 0.f, 0.f, 0.f};
#pragma unroll
    for (int r = 0; r < 4; ++r) { m_run[r] = -INFINITY; l_run[r] = 0.f; }

    const u16* kbh = ph_hi + (size_t)b * N_ * D_;
    const u16* kbl = ph_lo + (size_t)b * N_ * D_;
    const u16* vb  = gt    + (size_t)b * D_ * N_;

    for (int kv0 = 0; kv0 < N_; kv0 += 64) {
        __syncthreads();
        {
            int r = t >> 4, d0 = (t & 15) * 8;
#pragma unroll
            for (int i = 0; i < 4; ++i) {
                int rr = r + 16 * i;
                int off = rr * 128 + (d0 ^ ((rr & 7) << 3));
                *(bf16x8*)&Ksh[off] = *(const bf16x8*)(kbh + (size_t)(kv0 + rr) * D_ + d0);
                *(bf16x8*)&Ksl[off] = *(const bf16x8*)(kbl + (size_t)(kv0 + rr) * D_ + d0);
            }
            int d = t >> 3, k8 = (t & 7) * 8;
#pragma unroll
            for (int i = 0; i < 4; ++i) {
                int dd = d + 32 * i;
                *(bf16x8*)&Vt[dd * 64 + (k8 ^ ((dd & 7) << 3))] =
                    *(const bf16x8*)(vb + (size_t)dd * N_ + kv0 + k8);
            }
        }
        __syncthreads();

        // ---- S = Q K^T (hi/lo 3-term) ----
        f32x4 S[4];
#pragma unroll
        for (int tt = 0; tt < 4; ++tt) S[tt] = (f32x4){0.f, 0.f, 0.f, 0.f};
#pragma unroll
        for (int c = 0; c < 4; ++c) {
#pragma unroll
            for (int tt = 0; tt < 4; ++tt) {
                int row = 16 * tt + lq;
                int off = row * 128 + ((32 * c + 8 * lh) ^ ((row & 7) << 3));
                bf16x8 kh = *(const bf16x8*)&Ksh[off];
                bf16x8 kl = *(const bf16x8*)&Ksl[off];
                S[tt] = __builtin_amdgcn_mfma_f32_16x16x32_bf16(qfh[c], kh, S[tt], 0, 0, 0);
                S[tt] = __builtin_amdgcn_mfma_f32_16x16x32_bf16(qfl[c], kh, S[tt], 0, 0, 0);
                S[tt] = __builtin_amdgcn_mfma_f32_16x16x32_bf16(qfh[c], kl, S[tt], 0, 0, 0);
            }
        }

        // ---- online softmax (row q = 4*lh+r, col kv = 16*tt+lq) ----
#pragma unroll
        for (int r = 0; r < 4; ++r) {
            float mx = fmaxf(fmaxf(S[0][r], S[1][r]), fmaxf(S[2][r], S[3][r]));
#pragma unroll
            for (int d = 1; d < 16; d <<= 1) mx = fmaxf(mx, __shfl_xor(mx, d));
            float mn = fmaxf(m_run[r], mx);
            float al = __expf(m_run[r] - mn);
            m_run[r] = mn;
            float p0 = __expf(S[0][r] - mn);
            float p1 = __expf(S[1][r] - mn);
            float p2 = __expf(S[2][r] - mn);
            float p3 = __expf(S[3][r] - mn);
            float ls = p0 + p1 + p2 + p3;
#pragma unroll
            for (int d = 1; d < 16; d <<= 1) ls += __shfl_xor(ls, d);
            l_run[r] = l_run[r] * al + ls;
#pragma unroll
            for (int j = 0; j < 8; ++j) O[j][r] *= al;
            int q = 4 * lh + r;
            int swz = (q & 7) << 3;
            Pl[wv][q * 64 + (( 0 + lq) ^ swz)] = f2bf(p0);
            Pl[wv][q * 64 + ((16 + lq) ^ swz)] = f2bf(p1);
            Pl[wv][q * 64 + ((32 + lq) ^ swz)] = f2bf(p2);
            Pl[wv][q * 64 + ((48 + lq) ^ swz)] = f2bf(p3);
        }

        // ---- O += P V ----
#pragma unroll
        for (int c = 0; c < 2; ++c) {
            bf16x8 pf = *(const bf16x8*)&Pl[wv][lq * 64 + ((32 * c + 8 * lh) ^ ((lq & 7) << 3))];
#pragma unroll
            for (int j = 0; j < 8; ++j) {
                int row = 16 * j + lq;
                bf16x8 vf = *(const bf16x8*)&Vt[row * 64 + ((32 * c + 8 * lh) ^ ((row & 7) << 3))];
                O[j] = __builtin_amdgcn_mfma_f32_16x16x32_bf16(pf, vf, O[j], 0, 0, 0);
            }
        }
    }

    // ---- epilogue: y_t[b][ci][n] bf16, 8B packed stores ----
    float inv[4];
#pragma unroll
    for (int r = 0; r < 4; ++r) inv[r] = 1.f / l_run[r];
    u16* yt = y_t + (size_t)b * CI_ * N_;
#pragma unroll
    for (int j = 0; j < 8; ++j) {
        ushort4 pk;
        pk.x = f2bf(O[j][0] * inv[0]);
        pk.y = f2bf(O[j][1] * inv[1]);
        pk.z = f2bf(O[j][2] * inv[2]);
        pk.w = f2bf(O[j][3] * inv[3]);
        *(ushort4*)(yt + (size_t)(16 * j + lq) * N_ + q0 + 4 * lh) = pk;
    }
}

// ---------------------------------------------------------------------------
// Wz conv1x1 + BN partial sums.  grid (N/64, B, 2), block 256.
// w_y[b][c][n] = wz_b[c] + sum_ci y_t[b][ci][n] * wz_w[c][ci]
// ---------------------------------------------------------------------------
__global__ __launch_bounds__(256) void wz_kernel(
    const u16* __restrict__ y_t, const float* __restrict__ wz_w,
    const float* __restrict__ wz_b, float* __restrict__ w_y,
    float* __restrict__ sums)
{
    __shared__ u16 wlds[128 * 128];  // weights chunk [c_local][ci] bf16
    __shared__ u16 ylds[128][64];    // [ci][n] bf16
    const int n0 = blockIdx.x * 64, b = blockIdx.y, c0 = blockIdx.z * 128;
    const int t = threadIdx.x, lane = t & 63, wv = t >> 6;

    for (int i = 0; i < 16; ++i) {
        int e = i * 1024 + t * 4;
        float4 w = *(const float4*)(wz_w + (size_t)c0 * CI_ + e);
        unsigned u0 = (unsigned)f2bf(w.x) | ((unsigned)f2bf(w.y) << 16);
        unsigned u1 = (unsigned)f2bf(w.z) | ((unsigned)f2bf(w.w) << 16);
        *(uint2*)&wlds[e] = make_uint2(u0, u1);
    }
    const u16* ytb = y_t + (size_t)b * CI_ * N_ + n0;
    for (int i = 0; i < 4; ++i) {
        int flat = i * 256 + t;
        int row = flat >> 3, c8 = (flat & 7) * 8;
        *(bf16x8*)&ylds[row][c8] = *(const bf16x8*)(ytb + (size_t)row * N_ + c8);
    }
    __syncthreads();

    float acc[32];
#pragma unroll
    for (int k = 0; k < 32; ++k) acc[k] = wz_b[c0 + wv + 4 * k];

    for (int ci = 0; ci < CI_; ci += 4) {
        float v0 = bf2f(ylds[ci + 0][lane]);
        float v1 = bf2f(ylds[ci + 1][lane]);
        float v2 = bf2f(ylds[ci + 2][lane]);
        float v3 = bf2f(ylds[ci + 3][lane]);
#pragma unroll
        for (int k = 0; k < 32; ++k) {
            int cl = wv + 4 * k;
            uint2 w = *(const uint2*)&wlds[cl * 128 + ci];   // wave-uniform
            acc[k] += v0 * lo2f(w.x) + v1 * hi2f(w.x) + v2 * lo2f(w.y) + v3 * hi2f(w.y);
        }
    }

    const int n = n0 + lane;
#pragma unroll
    for (int k = 0; k < 32; ++k) {
        int c = c0 + wv + 4 * k;
        float a = acc[k];
        w_y[((size_t)b * C_ + c) * N_ + n] = a;
        float s = a, q = a * a;
#pragma unroll
        for (int d = 1; d < 64; d <<= 1) {
            s += __shfl_xor(s, d);
            q += __shfl_xor(q, d);
        }
        if (lane == 0) {
            atomicAdd(&sums[c], s);
            atomicAdd(&sums[C_ + c], q);
        }
    }
}

// ---------------------------------------------------------------------------
// BN finalize + residual
// ---------------------------------------------------------------------------
__global__ __launch_bounds__(256) void final_kernel(
    const float* __restrict__ w_y, const float* __restrict__ src,
    const float* __restrict__ gamma, const float* __restrict__ beta,
    const float* __restrict__ sums, float* __restrict__ out)
{
    const float invN = 1.0f / (float)(B_ * N_);
    const size_t tot4 = (size_t)B_ * C_ * N_ / 4;
    size_t stride = (size_t)gridDim.x * blockDim.x;
    for (size_t i4 = (size_t)blockIdx.x * blockDim.x + threadIdx.x; i4 < tot4; i4 += stride) {
        size_t i = i4 * 4;
        int c = (int)((i / N_) % C_);
        float mean  = sums[c] * invN;
        float var   = sums[C_ + c] * invN - mean * mean;
        float scale = rsqrtf(var + 1e-5f) * gamma[c];
        float bb    = beta[c];
        float4 w = *(const float4*)(w_y + i);
        float4 s = *(const float4*)(src + i);
        float4 o;
        o.x = (w.x - mean) * scale + bb + s.x;
        o.y = (w.y - mean) * scale + bb + s.y;
        o.z = (w.z - mean) * scale + bb + s.z;
        o.w = (w.w - mean) * scale + bb + s.w;
        *(float4*)((float*)out + i) = o;
    }
}

extern "C" void kernel_launch(void* const* d_in, const int* in_sizes, int n_in,
                              void* d_out, int out_size, void* d_ws, size_t ws_size,
                              hipStream_t stream)
{
    const float* x     = (const float*)d_in[0];
    const float* src   = (const float*)d_in[1];
    const float* g_w   = (const float*)d_in[2];
    const float* g_b   = (const float*)d_in[3];
    const float* th_w  = (const float*)d_in[4];
    const float* th_b  = (const float*)d_in[5];
    const float* ph_w  = (const float*)d_in[6];
    const float* ph_b  = (const float*)d_in[7];
    const float* wz_w  = (const float*)d_in[8];
    const float* wz_b  = (const float*)d_in[9];
    const float* gamma = (const float*)d_in[10];
    const float* beta  = (const float*)d_in[11];

    char* ws = (char*)d_ws;
    u16*   th_hi = (u16*)(ws + (0u  << 20));   // 4 MB  (dead after attn)
    u16*   th_lo = (u16*)(ws + (4u  << 20));   // 4 MB  (dead after attn)
    u16*   ph_hi = (u16*)(ws + (8u  << 20));   // 4 MB  (dead after attn)
    u16*   ph_lo = (u16*)(ws + (12u << 20));   // 4 MB  (dead after attn)
    u16*   gt    = (u16*)(ws + (16u << 20));   // 4 MB  (dead after attn)
    u16*   y_t   = (u16*)(ws + (20u << 20));   // 4 MB
    float* w_y   = (float*)(ws + (0u  << 20)); // 16 MB, aliases th/ph (dead)
    float* sums  = (float*)(ws + (24u << 20)); // 2 KB

    hipMemsetAsync(sums, 0, 2 * C_ * sizeof(float), stream);

    embed_kernel<<<dim3(64, 4, 3), 256, 65536, stream>>>(
        x, src, g_w, g_b, th_w, th_b, ph_w, ph_b,
        th_hi, th_lo, ph_hi, ph_lo, gt);
    attn_kernel<<<dim3(64, 4), 256, 0, stream>>>(
        th_hi, th_lo, ph_hi, ph_lo, gt, y_t);
    wz_kernel<<<dim3(64, 4, 2), 256, 0, stream>>>(y_t, wz_w, wz_b, w_y, sums);
    final_kernel<<<2048, 256, 0, stream>>>(w_y, src, gamma, beta, sums, (float*)d_out);
}

// Round 4
// 182.931 us; speedup vs baseline: 7.7810x; 4.1148x over previous
//
#include <hip/hip_runtime.h>
#include <math.h>

#define B_  4
#define C_  256
#define CI_ 128
#define N_  4096
#define D_  128
#define KVSPLIT 2
#define KVHALF  (N_ / KVSPLIT)

typedef short bf16x8 __attribute__((ext_vector_type(8)));
typedef float f32x4 __attribute__((ext_vector_type(4)));
typedef unsigned short u16;

__device__ __forceinline__ u16 f2bf(float x) {
    union { float f; unsigned u; } v; v.f = x;
    unsigned r = v.u + 0x7FFFu + ((v.u >> 16) & 1u);
    return (u16)(r >> 16);
}
__device__ __forceinline__ float bf2f(u16 u) {
    union { unsigned u; float f; } v; v.u = ((unsigned)u) << 16; return v.f;
}

// ---------------------------------------------------------------------------
// Embedding conv1x1 as hi/lo bf16 MFMA GEMM.
// out[b][n][ci] = bias[ci] + sum_c w[ci][c] * in[b][c][n]
// grid (N/64, B, 3), block 256 (4 waves, 2 m-frags each).
// B-operand: input tile transposed to LDS [64 n][stride 40 u16] (conflict-free).
// A-operand: weight rows straight from global (f32 -> bf16 h/l in regs).
// which 0: theta(x) -> th_hi/th_lo [n][ci]; 1: phi(src) -> ph_hi/lo;
// which 2: g(src) -> gt [ci][n].
// ---------------------------------------------------------------------------
__global__ __launch_bounds__(256) void embed_kernel(
    const float* __restrict__ x, const float* __restrict__ src,
    const float* __restrict__ g_w, const float* __restrict__ g_b,
    const float* __restrict__ th_w, const float* __restrict__ th_b,
    const float* __restrict__ ph_w, const float* __restrict__ ph_b,
    u16* __restrict__ th_hi, u16* __restrict__ th_lo,
    u16* __restrict__ ph_hi, u16* __restrict__ ph_lo,
    u16* __restrict__ gt)
{
    __shared__ u16 xh[64 * 40];
    __shared__ u16 xl[64 * 40];

    const int n0 = blockIdx.x * 64, b = blockIdx.y, which = blockIdx.z;
    const float *in, *wm, *bias;
    if (which == 0)      { in = x;   wm = th_w; bias = th_b; }
    else if (which == 1) { in = src; wm = ph_w; bias = ph_b; }
    else                 { in = src; wm = g_w;  bias = g_b;  }

    const int t = threadIdx.x, lane = t & 63, wv = t >> 6;
    const int lq = lane & 15, lh = lane >> 4;
    const int mf0 = wv * 2;                 // wave owns m-frags mf0, mf0+1

    f32x4 acc[2][4];
#pragma unroll
    for (int m = 0; m < 2; ++m) {
        float b0 = bias[16 * (mf0 + m) + 4 * lh + 0];
        float b1 = bias[16 * (mf0 + m) + 4 * lh + 1];
        float b2 = bias[16 * (mf0 + m) + 4 * lh + 2];
        float b3 = bias[16 * (mf0 + m) + 4 * lh + 3];
#pragma unroll
        for (int s = 0; s < 4; ++s) acc[m][s] = (f32x4){b0, b1, b2, b3};
    }

    const float* colbase = in + (size_t)b * C_ * N_ + n0;
    const int cq = t >> 6;                  // 0..3 (c-group for staging)

    for (int k = 0; k < 8; ++k) {
        const int c0 = k * 32;
        __syncthreads();
        // stage: xT[n][c_local] hi/lo, stride 40 u16 (80B rows, 16B-aligned)
#pragma unroll
        for (int p = 0; p < 2; ++p) {
            int cl = 16 * p + 4 * cq;
            float v0 = colbase[(size_t)(c0 + cl + 0) * N_ + lane];
            float v1 = colbase[(size_t)(c0 + cl + 1) * N_ + lane];
            float v2 = colbase[(size_t)(c0 + cl + 2) * N_ + lane];
            float v3 = colbase[(size_t)(c0 + cl + 3) * N_ + lane];
            u16 h0 = f2bf(v0), h1 = f2bf(v1), h2 = f2bf(v2), h3 = f2bf(v3);
            ushort4 hv = {h0, h1, h2, h3};
            ushort4 lv = {f2bf(v0 - bf2f(h0)), f2bf(v1 - bf2f(h1)),
                          f2bf(v2 - bf2f(h2)), f2bf(v3 - bf2f(h3))};
            *(ushort4*)&xh[lane * 40 + cl] = hv;
            *(ushort4*)&xl[lane * 40 + cl] = lv;
        }
        __syncthreads();

        // A-frags: w[16*mf+lq][c0 + 8*lh .. +7], f32 -> bf16 h/l
        bf16x8 wh[2], wl[2];
#pragma unroll
        for (int m = 0; m < 2; ++m) {
            const float* wp = wm + (size_t)(16 * (mf0 + m) + lq) * C_ + c0 + 8 * lh;
            float4 a = *(const float4*)wp;
            float4 bq = *(const float4*)(wp + 4);
            float wf[8] = {a.x, a.y, a.z, a.w, bq.x, bq.y, bq.z, bq.w};
#pragma unroll
            for (int j = 0; j < 8; ++j) {
                u16 h = f2bf(wf[j]);
                wh[m][j] = (short)h;
                wl[m][j] = (short)f2bf(wf[j] - bf2f(h));
            }
        }
#pragma unroll
        for (int s = 0; s < 4; ++s) {
            bf16x8 xhf = *(const bf16x8*)&xh[(16 * s + lq) * 40 + 8 * lh];
            bf16x8 xlf = *(const bf16x8*)&xl[(16 * s + lq) * 40 + 8 * lh];
#pragma unroll
            for (int m = 0; m < 2; ++m) {
                acc[m][s] = __builtin_amdgcn_mfma_f32_16x16x32_bf16(wh[m], xhf, acc[m][s], 0, 0, 0);
                acc[m][s] = __builtin_amdgcn_mfma_f32_16x16x32_bf16(wl[m], xhf, acc[m][s], 0, 0, 0);
                acc[m][s] = __builtin_amdgcn_mfma_f32_16x16x32_bf16(wh[m], xlf, acc[m][s], 0, 0, 0);
            }
        }
    }

    // epilogue. D-layout: col(n) = lq, row(ci) = 16*mf + 4*lh + reg
    if (which < 2) {
        u16* oh = (which == 0 ? th_hi : ph_hi) + (size_t)b * N_ * CI_;
        u16* ol = (which == 0 ? th_lo : ph_lo) + (size_t)b * N_ * CI_;
#pragma unroll
        for (int m = 0; m < 2; ++m)
#pragma unroll
            for (int s = 0; s < 4; ++s) {
                ushort4 hv, lv;
                u16 h;
                h = f2bf(acc[m][s][0]); hv.x = h; lv.x = f2bf(acc[m][s][0] - bf2f(h));
                h = f2bf(acc[m][s][1]); hv.y = h; lv.y = f2bf(acc[m][s][1] - bf2f(h));
                h = f2bf(acc[m][s][2]); hv.z = h; lv.z = f2bf(acc[m][s][2] - bf2f(h));
                h = f2bf(acc[m][s][3]); hv.w = h; lv.w = f2bf(acc[m][s][3] - bf2f(h));
                size_t ofs = (size_t)(n0 + 16 * s + lq) * CI_ + 16 * (mf0 + m) + 4 * lh;
                *(ushort4*)(oh + ofs) = hv;
                *(ushort4*)(ol + ofs) = lv;
            }
    } else {
        u16* gb = gt + (size_t)b * CI_ * N_;
#pragma unroll
        for (int m = 0; m < 2; ++m)
#pragma unroll
            for (int s = 0; s < 4; ++s)
#pragma unroll
                for (int r = 0; r < 4; ++r)
                    gb[(size_t)(16 * (mf0 + m) + 4 * lh + r) * N_ + n0 + 16 * s + lq] =
                        f2bf(acc[m][s][r]);
    }
}

// ---------------------------------------------------------------------------
// Flash attention, swapped-operand MFMA, kv-split x2.
// grid (N/64, B, KVSPLIT), block 256 (4 waves x 16 q).
// S^T[tt] = mfma(kf, qf): lane holds S(q=lq, kv=16tt+4lh+r) -> per-lane softmax.
// P stored as ushort4 with even-XOR slot swizzle; PV: O = mfma(vf, pf, O)
// keeps q=lq per lane (alpha rescale is lane-local).
// Outputs f32 partials (unnormalized O, m, l) for the merge kernel.
// ---------------------------------------------------------------------------
__global__ __launch_bounds__(256) void attn_kernel(
    const u16* __restrict__ th_hi, const u16* __restrict__ th_lo,
    const u16* __restrict__ ph_hi, const u16* __restrict__ ph_lo,
    const u16* __restrict__ gt, float* __restrict__ part, float* __restrict__ ml)
{
    __shared__ u16 Ksh[64 * 128];
    __shared__ u16 Ksl[64 * 128];
    __shared__ u16 Vt[128 * 64];
    __shared__ u16 Pl[4][16 * 64];

    const int n0 = blockIdx.x * 64, b = blockIdx.y, half = blockIdx.z;
    const int t = threadIdx.x, wv = t >> 6, lane = t & 63;
    const int lq = lane & 15, lh = lane >> 4;
    const int q0 = n0 + wv * 16;

    bf16x8 qfh[4], qfl[4];
    {
        const u16* qph = th_hi + ((size_t)b * N_ + q0 + lq) * D_ + 8 * lh;
        const u16* qpl = th_lo + ((size_t)b * N_ + q0 + lq) * D_ + 8 * lh;
#pragma unroll
        for (int c = 0; c < 4; ++c) {
            qfh[c] = *(const bf16x8*)(qph + 32 * c);
            qfl[c] = *(const bf16x8*)(qpl + 32 * c);
        }
    }

    f32x4 Ot[8];
#pragma unroll
    for (int j = 0; j < 8; ++j) Ot[j] = (f32x4){0.f, 0.f, 0.f, 0.f};
    float m_run = -INFINITY, l_run = 0.f;

    const u16* kbh = ph_hi + (size_t)b * N_ * D_ + (size_t)half * KVHALF * D_;
    const u16* kbl = ph_lo + (size_t)b * N_ * D_ + (size_t)half * KVHALF * D_;
    const u16* vb  = gt    + (size_t)b * D_ * N_ + half * KVHALF;

    for (int kv0 = 0; kv0 < KVHALF; kv0 += 64) {
        __syncthreads();
        {
            int r = t >> 4, d0 = (t & 15) * 8;
#pragma unroll
            for (int i = 0; i < 4; ++i) {
                int rr = r + 16 * i;
                int off = rr * 128 + (d0 ^ ((rr & 7) << 3));
                *(bf16x8*)&Ksh[off] = *(const bf16x8*)(kbh + (size_t)(kv0 + rr) * D_ + d0);
                *(bf16x8*)&Ksl[off] = *(const bf16x8*)(kbl + (size_t)(kv0 + rr) * D_ + d0);
            }
            int d = t >> 3, k8 = (t & 7) * 8;
#pragma unroll
            for (int i = 0; i < 4; ++i) {
                int dd = d + 32 * i;
                *(bf16x8*)&Vt[dd * 64 + (k8 ^ ((dd & 7) << 3))] =
                    *(const bf16x8*)(vb + (size_t)dd * N_ + kv0 + k8);
            }
        }
        __syncthreads();

        // ---- S^T = K Q^T (hi/lo 3-term): lane: q = lq, kv = 16*tt + 4*lh + r
        f32x4 S[4];
#pragma unroll
        for (int tt = 0; tt < 4; ++tt) S[tt] = (f32x4){0.f, 0.f, 0.f, 0.f};
#pragma unroll
        for (int c = 0; c < 4; ++c) {
#pragma unroll
            for (int tt = 0; tt < 4; ++tt) {
                int row = 16 * tt + lq;
                int off = row * 128 + ((32 * c + 8 * lh) ^ ((row & 7) << 3));
                bf16x8 kh = *(const bf16x8*)&Ksh[off];
                bf16x8 kl = *(const bf16x8*)&Ksl[off];
                S[tt] = __builtin_amdgcn_mfma_f32_16x16x32_bf16(kh, qfh[c], S[tt], 0, 0, 0);
                S[tt] = __builtin_amdgcn_mfma_f32_16x16x32_bf16(kh, qfl[c], S[tt], 0, 0, 0);
                S[tt] = __builtin_amdgcn_mfma_f32_16x16x32_bf16(kl, qfh[c], S[tt], 0, 0, 0);
            }
        }

        // ---- per-lane online softmax for q = lq ----
        float mx = fmaxf(fmaxf(S[0][0], S[0][1]), fmaxf(S[0][2], S[0][3]));
#pragma unroll
        for (int tt = 1; tt < 4; ++tt)
            mx = fmaxf(mx, fmaxf(fmaxf(S[tt][0], S[tt][1]), fmaxf(S[tt][2], S[tt][3])));
        mx = fmaxf(mx, __shfl_xor(mx, 16));
        mx = fmaxf(mx, __shfl_xor(mx, 32));
        float mn = fmaxf(m_run, mx);
        float al = __expf(m_run - mn);
        m_run = mn;
        float ls = 0.f;
#pragma unroll
        for (int tt = 0; tt < 4; ++tt) {
            float p0 = __expf(S[tt][0] - mn);
            float p1 = __expf(S[tt][1] - mn);
            float p2 = __expf(S[tt][2] - mn);
            float p3 = __expf(S[tt][3] - mn);
            ls += p0 + p1 + p2 + p3;
            ushort4 pk = {f2bf(p0), f2bf(p1), f2bf(p2), f2bf(p3)};
            // kv cols 16*tt+4*lh..+3 -> 8B slot (4*tt+lh) ^ (lq&6)  (even XOR)
            *(ushort4*)&Pl[wv][lq * 64 + 4 * ((4 * tt + lh) ^ (lq & 6))] = pk;
        }
        ls += __shfl_xor(ls, 16);
        ls += __shfl_xor(ls, 32);
        l_run = l_run * al + ls;
#pragma unroll
        for (int j = 0; j < 8; ++j) Ot[j] *= al;

        // ---- O^T += V^T P^T : lane: q = lq, d = 16*j + 4*lh + r ----
#pragma unroll
        for (int cc = 0; cc < 2; ++cc) {
            bf16x8 pf = *(const bf16x8*)&Pl[wv][lq * 64 + 8 * ((4 * cc + lh) ^ ((lq >> 1) & 3))];
#pragma unroll
            for (int j = 0; j < 8; ++j) {
                int row = 16 * j + lq;
                bf16x8 vf = *(const bf16x8*)&Vt[row * 64 + ((32 * cc + 8 * lh) ^ ((row & 7) << 3))];
                Ot[j] = __builtin_amdgcn_mfma_f32_16x16x32_bf16(vf, pf, Ot[j], 0, 0, 0);
            }
        }
    }

    // ---- partial store: part[half][b][q][d] f32, ml[half][b][q] = {m,l} ----
    float* pb = part + ((size_t)half * B_ + b) * N_ * D_ + (size_t)(q0 + lq) * D_;
#pragma unroll
    for (int j = 0; j < 8; ++j)
        *(f32x4*)(pb + 16 * j + 4 * lh) = Ot[j];
    if (lh == 0) {
        float* mp = ml + (((size_t)half * B_ + b) * N_ + q0 + lq) * 2;
        mp[0] = m_run; mp[1] = l_run;
    }
}

// ---------------------------------------------------------------------------
// Merge kv-split partials -> y[b][n][ci] bf16
// grid (N/64, B), block 256.
// ---------------------------------------------------------------------------
__global__ __launch_bounds__(256) void merge_kernel(
    const float* __restrict__ part, const float* __restrict__ ml,
    u16* __restrict__ y)
{
    const int n0 = blockIdx.x * 64, b = blockIdx.y;
    const int t = threadIdx.x;
    const int d4 = (t & 31) * 4, qi = t >> 5;
#pragma unroll
    for (int i = 0; i < 8; ++i) {
        int q = n0 + qi * 8 + i;
        size_t i0 = ((size_t)0 * B_ + b) * N_ + q;
        size_t i1 = ((size_t)1 * B_ + b) * N_ + q;
        float2 ml0 = *(const float2*)(ml + i0 * 2);
        float2 ml1 = *(const float2*)(ml + i1 * 2);
        float m = fmaxf(ml0.x, ml1.x);
        float w0 = __expf(ml0.x - m), w1 = __expf(ml1.x - m);
        float inv = 1.f / (w0 * ml0.y + w1 * ml1.y);
        f32x4 o0 = *(const f32x4*)(part + i0 * D_ + d4);
        f32x4 o1 = *(const f32x4*)(part + i1 * D_ + d4);
        ushort4 pk;
        pk.x = f2bf((o0[0] * w0 + o1[0] * w1) * inv);
        pk.y = f2bf((o0[1] * w0 + o1[1] * w1) * inv);
        pk.z = f2bf((o0[2] * w0 + o1[2] * w1) * inv);
        pk.w = f2bf((o0[3] * w0 + o1[3] * w1) * inv);
        *(ushort4*)(y + ((size_t)b * N_ + q) * CI_ + d4) = pk;
    }
}

// ---------------------------------------------------------------------------
// Wz conv1x1 (MFMA) + BN partial sums. grid (N/64, B), block 256.
// w_y[b][c][n] = wz_b[c] + sum_ci wz_w[c][ci] * y[b][n][ci]
// ---------------------------------------------------------------------------
__global__ __launch_bounds__(256) void wz_kernel(
    const u16* __restrict__ y, const float* __restrict__ wz_w,
    const float* __restrict__ wz_b, float* __restrict__ w_y,
    float* __restrict__ sums)
{
    __shared__ u16 ylds[64 * 128];       // [n][ci], 16B-slot s ^= (n&7)
    const int n0 = blockIdx.x * 64, b = blockIdx.y;
    const int t = threadIdx.x, lane = t & 63, wv = t >> 6;
    const int lq = lane & 15, lh = lane >> 4;

#pragma unroll
    for (int i = 0; i < 4; ++i) {
        int flat = i * 256 + t;
        int row = flat >> 4, s = flat & 15;
        bf16x8 v = *(const bf16x8*)(y + ((size_t)(b * N_ + n0 + row)) * CI_ + 8 * s);
        *(bf16x8*)&ylds[row * 128 + 8 * (s ^ (row & 7))] = v;
    }
    __syncthreads();

    f32x4 acc[4][4];                     // [mm][s], c = 16*(4*wv+mm)+4*lh+r
#pragma unroll
    for (int mm = 0; mm < 4; ++mm) {
        float b0 = wz_b[16 * (4 * wv + mm) + 4 * lh + 0];
        float b1 = wz_b[16 * (4 * wv + mm) + 4 * lh + 1];
        float b2 = wz_b[16 * (4 * wv + mm) + 4 * lh + 2];
        float b3 = wz_b[16 * (4 * wv + mm) + 4 * lh + 3];
#pragma unroll
        for (int s = 0; s < 4; ++s) acc[mm][s] = (f32x4){b0, b1, b2, b3};
    }

#pragma unroll
    for (int k = 0; k < 4; ++k) {
        bf16x8 wf[4];
#pragma unroll
        for (int mm = 0; mm < 4; ++mm) {
            const float* wp = wz_w + (size_t)(16 * (4 * wv + mm) + lq) * CI_ + 32 * k + 8 * lh;
            float4 a = *(const float4*)wp;
            float4 bq = *(const float4*)(wp + 4);
            wf[mm][0] = (short)f2bf(a.x);  wf[mm][1] = (short)f2bf(a.y);
            wf[mm][2] = (short)f2bf(a.z);  wf[mm][3] = (short)f2bf(a.w);
            wf[mm][4] = (short)f2bf(bq.x); wf[mm][5] = (short)f2bf(bq.y);
            wf[mm][6] = (short)f2bf(bq.z); wf[mm][7] = (short)f2bf(bq.w);
        }
#pragma unroll
        for (int s = 0; s < 4; ++s) {
            int row = 16 * s + lq;
            bf16x8 yf = *(const bf16x8*)&ylds[row * 128 + 8 * ((4 * k + lh) ^ (row & 7))];
#pragma unroll
            for (int mm = 0; mm < 4; ++mm)
                acc[mm][s] = __builtin_amdgcn_mfma_f32_16x16x32_bf16(wf[mm], yf, acc[mm][s], 0, 0, 0);
        }
    }

    // store w_y + BN partial sums
#pragma unroll
    for (int mm = 0; mm < 4; ++mm) {
        int cb = 16 * (4 * wv + mm) + 4 * lh;
#pragma unroll
        for (int s = 0; s < 4; ++s) {
            int n = n0 + 16 * s + lq;
#pragma unroll
            for (int r = 0; r < 4; ++r)
                w_y[((size_t)b * C_ + cb + r) * N_ + n] = acc[mm][s][r];
        }
#pragma unroll
        for (int r = 0; r < 4; ++r) {
            float sv = acc[mm][0][r] + acc[mm][1][r] + acc[mm][2][r] + acc[mm][3][r];
            float qv = acc[mm][0][r] * acc[mm][0][r] + acc[mm][1][r] * acc[mm][1][r]
                     + acc[mm][2][r] * acc[mm][2][r] + acc[mm][3][r] * acc[mm][3][r];
#pragma unroll
            for (int d = 1; d < 16; d <<= 1) {
                sv += __shfl_xor(sv, d);
                qv += __shfl_xor(qv, d);
            }
            if (lq == 0) {
                atomicAdd(&sums[cb + r], sv);
                atomicAdd(&sums[C_ + cb + r], qv);
            }
        }
    }
}

// ---------------------------------------------------------------------------
// BN finalize + residual
// ---------------------------------------------------------------------------
__global__ __launch_bounds__(256) void final_kernel(
    const float* __restrict__ w_y, const float* __restrict__ src,
    const float* __restrict__ gamma, const float* __restrict__ beta,
    const float* __restrict__ sums, float* __restrict__ out)
{
    const float invN = 1.0f / (float)(B_ * N_);
    const size_t tot4 = (size_t)B_ * C_ * N_ / 4;
    size_t stride = (size_t)gridDim.x * blockDim.x;
    for (size_t i4 = (size_t)blockIdx.x * blockDim.x + threadIdx.x; i4 < tot4; i4 += stride) {
        size_t i = i4 * 4;
        int c = (int)((i / N_) % C_);
        float mean  = sums[c] * invN;
        float var   = sums[C_ + c] * invN - mean * mean;
        float scale = rsqrtf(var + 1e-5f) * gamma[c];
        float bb    = beta[c];
        float4 w = *(const float4*)(w_y + i);
        float4 s = *(const float4*)(src + i);
        float4 o;
        o.x = (w.x - mean) * scale + bb + s.x;
        o.y = (w.y - mean) * scale + bb + s.y;
        o.z = (w.z - mean) * scale + bb + s.z;
        o.w = (w.w - mean) * scale + bb + s.w;
        *(float4*)((float*)out + i) = o;
    }
}

extern "C" void kernel_launch(void* const* d_in, const int* in_sizes, int n_in,
                              void* d_out, int out_size, void* d_ws, size_t ws_size,
                              hipStream_t stream)
{
    const float* x     = (const float*)d_in[0];
    const float* src   = (const float*)d_in[1];
    const float* g_w   = (const float*)d_in[2];
    const float* g_b   = (const float*)d_in[3];
    const float* th_w  = (const float*)d_in[4];
    const float* th_b  = (const float*)d_in[5];
    const float* ph_w  = (const float*)d_in[6];
    const float* ph_b  = (const float*)d_in[7];
    const float* wz_w  = (const float*)d_in[8];
    const float* wz_b  = (const float*)d_in[9];
    const float* gamma = (const float*)d_in[10];
    const float* beta  = (const float*)d_in[11];

    char* ws = (char*)d_ws;
    u16*   th_hi = (u16*)(ws + (0u  << 20));    // 4 MB
    u16*   th_lo = (u16*)(ws + (4u  << 20));    // 4 MB
    u16*   ph_hi = (u16*)(ws + (8u  << 20));    // 4 MB
    u16*   ph_lo = (u16*)(ws + (12u << 20));    // 4 MB
    u16*   gt    = (u16*)(ws + (16u << 20));    // 4 MB
    float* part  = (float*)(ws + (20u << 20));  // 16 MB [2][B][N][D]
    float* mlbuf = (float*)(ws + (36u << 20));  // 256 KB
    u16*   y     = (u16*)(ws + (0u  << 20));    // 4 MB, aliases th_hi (dead)
    float* w_y   = (float*)(ws + (20u << 20));  // 16 MB, aliases part (dead)
    float* sums  = (float*)(ws + (36u << 20) + (256u << 10)); // 2 KB

    hipMemsetAsync(sums, 0, 2 * C_ * sizeof(float), stream);

    embed_kernel<<<dim3(64, 4, 3), 256, 0, stream>>>(
        x, src, g_w, g_b, th_w, th_b, ph_w, ph_b,
        th_hi, th_lo, ph_hi, ph_lo, gt);
    attn_kernel<<<dim3(64, 4, KVSPLIT), 256, 0, stream>>>(
        th_hi, th_lo, ph_hi, ph_lo, gt, part, mlbuf);
    merge_kernel<<<dim3(64, 4), 256, 0, stream>>>(part, mlbuf, y);
    wz_kernel<<<dim3(64, 4), 256, 0, stream>>>(y, wz_w, wz_b, w_y, sums);
    final_kernel<<<2048, 256, 0, stream>>>(w_y, src, gamma, beta, sums, (float*)d_out);
}